// Round 9
// baseline (289.335 us; speedup 1.0000x reference)
//
#include <hip/hip_runtime.h>
#include <math.h>

// Sparsemax along axis 0 of z = -exp(a)*x, x: (4096, 8192) f32 row-major.
//
// R10: fuse auxiliary dispatches into the mandatory streams. 6 -> 4 dispatches.
// R9 analysis: all kernels < 79us (top-5 = harness fills only); our budget
// ~104us vs a 41us HBM floor (read 128 MiB + write 128 MiB). The slack is in
// dispatches that move no mandatory bytes:
//   - memset(out) fused into the filter pass (it already walks the full
//     index space sequentially; emit the zeros there with nt stores).
//   - memset(cnt) fused into k_pmax's prologue.
//   - k_reduce made coalesced (thread-per-column) instead of 32KB-strided.
// Candidate algebra unchanged from R9 (proven): threshold in x-units
// thrx = (s*colmin_x - 1.000002)/s gives a strict superset of the support
// (z > colmax-1 <=> x < thrx, s<0); ~4.5 candidates/col, CAPC=64; K>CAPC
// falls back to the exact full-column Michelot (correctness never
// statistical).
//
// Pipeline:
//   A k_pmax:      256 blocks x 1024 thr; block = 16-row panel read fully
//                  sequentially; col-min partials -> pminx[256][8192];
//                  prologue zeroes cnt.
//   B k_reduce:    32 blocks x 256 thr, one col/thread, coalesced reduction
//                  of 256 partials -> thrx[col].
//   C k_filterzero:512 blocks x 8-row panels, sequential x read (L3-hot),
//                  nt-store ZEROS to all of out, scatter (z,row) candidate
//                  pairs for x < thrx (thresholds staged in 32KB LDS).
//   D k_solve:     one wave/col exact Michelot on <=64 candidates, scatter
//                  ~5 nonzeros over the zeroed out.
//
// ws: [0,512K) cnt int[8192*16]; [512K,544K) thrx f32[8192];
//     [1M,9M) pminx f32[256][8192]; [9M,13M) cand float2[8192][64].

constexpr int ROWS = 4096;
constexpr int COLS = 8192;
constexpr int CAPC = 64;           // candidate slots per column
constexpr int CPAD = 16;           // cnt stride (ints) = one 64B line per col

constexpr int PANA = 16;           // rows per A panel
constexpr int NPA  = ROWS / PANA;  // 256 partials
constexpr int PANC = 8;            // rows per C panel

typedef float vfloat4 __attribute__((ext_vector_type(4)));

// ---------------- A: sequential col-min partials (+ cnt zero) ----------------
__global__ __launch_bounds__(1024)
void k_pmax(const float* __restrict__ x, float* __restrict__ pminx,
            int* __restrict__ cnt)
{
    const int t = threadIdx.x;
    const int b = blockIdx.x;

    // fused memset(cnt): 256 blocks x 128 int4 = 131072 ints
    if (t < 128)
        reinterpret_cast<int4*>(cnt)[b * 128 + t] = make_int4(0, 0, 0, 0);

    const long row0 = (long)b * PANA;

    float m[2][4];
#pragma unroll
    for (int ch = 0; ch < 2; ++ch)
#pragma unroll
        for (int j = 0; j < 4; ++j) m[ch][j] = 3.0e38f;

    for (int r = 0; r < PANA; ++r) {
        const long rb = (row0 + r) * COLS;
#pragma unroll
        for (int ch = 0; ch < 2; ++ch) {
            const int col = ch * 4096 + t * 4;
            const float4 v = *reinterpret_cast<const float4*>(x + rb + col);
            m[ch][0] = fminf(m[ch][0], v.x);
            m[ch][1] = fminf(m[ch][1], v.y);
            m[ch][2] = fminf(m[ch][2], v.z);
            m[ch][3] = fminf(m[ch][3], v.w);
        }
    }
#pragma unroll
    for (int ch = 0; ch < 2; ++ch) {
        float4 o = make_float4(m[ch][0], m[ch][1], m[ch][2], m[ch][3]);
        *reinterpret_cast<float4*>(pminx + (long)b * COLS + ch * 4096 + t * 4) = o;
    }
}

// ------------- B: coalesced reduce -> per-col threshold (x-units) ----------
__global__ __launch_bounds__(256)
void k_reduce(const float* __restrict__ pminx, const float* __restrict__ a,
              float* __restrict__ thrx)
{
    const int col = blockIdx.x * 256 + threadIdx.x;
    float m = 3.0e38f;
    for (int p = 0; p < NPA; ++p)
        m = fminf(m, pminx[(long)p * COLS + col]);     // coalesced across threads
    const float s = -expf(a[0]);                        // s < 0
    // z > colmax_z - 1  <=>  x < (colmax_z - 1)/s ; 2e-6 margin for f32 rounding
    thrx[col] = (s * m - 1.000002f) / s;
}

// ------- C: sequential filter scan + fused zero-fill of out ---------------
__global__ __launch_bounds__(512, 2)
void k_filterzero(const float* __restrict__ x, const float* __restrict__ a,
                  const float* __restrict__ thrx,
                  int* __restrict__ cnt, float2* __restrict__ cand,
                  float* __restrict__ out)
{
    __shared__ float tl[COLS];      // 32 KB of per-col thresholds
    const int t = threadIdx.x;
    for (int i = t; i < COLS / 4; i += 512)
        reinterpret_cast<float4*>(tl)[i] =
            reinterpret_cast<const float4*>(thrx)[i];
    __syncthreads();

    const long row0 = (long)blockIdx.x * PANC;
    const float s   = -expf(a[0]);
    const vfloat4 z4 = {0.f, 0.f, 0.f, 0.f};

    for (int r = 0; r < PANC; ++r) {
        const int  row = (int)row0 + r;
        const long rb  = (long)row * COLS;
#pragma unroll
        for (int ch = 0; ch < 4; ++ch) {
            const int col = ch * 2048 + t * 4;
            const float4 v  = *reinterpret_cast<const float4*>(x + rb + col);
            const float4 th = *reinterpret_cast<const float4*>(tl + col);
            __builtin_nontemporal_store(z4,
                reinterpret_cast<vfloat4*>(out + rb + col));
            if (v.x < th.x) { int i = atomicAdd(&cnt[(col + 0) * CPAD], 1);
                if (i < CAPC) cand[(long)(col + 0) * CAPC + i] =
                    make_float2(s * v.x, __int_as_float(row)); }
            if (v.y < th.y) { int i = atomicAdd(&cnt[(col + 1) * CPAD], 1);
                if (i < CAPC) cand[(long)(col + 1) * CAPC + i] =
                    make_float2(s * v.y, __int_as_float(row)); }
            if (v.z < th.z) { int i = atomicAdd(&cnt[(col + 2) * CPAD], 1);
                if (i < CAPC) cand[(long)(col + 2) * CAPC + i] =
                    make_float2(s * v.z, __int_as_float(row)); }
            if (v.w < th.w) { int i = atomicAdd(&cnt[(col + 3) * CPAD], 1);
                if (i < CAPC) cand[(long)(col + 3) * CAPC + i] =
                    make_float2(s * v.w, __int_as_float(row)); }
        }
    }
}

// ---------------- D: one wave per column, Michelot + scatter --------------
__global__ __launch_bounds__(256, 4)
void k_solve(const int* __restrict__ cnt, const float2* __restrict__ cand,
             const float* __restrict__ x, const float* __restrict__ a,
             float* __restrict__ out)
{
    const int lane = threadIdx.x & 63;
    const int col  = blockIdx.x * 4 + (threadIdx.x >> 6);
    const int K    = cnt[col * CPAD];

    if (K <= CAPC) {
        float v = -3.3e38f; int row = 0;
        if (lane < K) {
            const float2 p = cand[(long)col * CAPC + lane];
            v = p.x; row = __float_as_int(p.y);
        }
        float t = -3.0e38f, prev = 0.f;
        for (int it = 0; it < CAPC + 4; ++it) {
            const bool act = v > t;
            float ss = act ? v : 0.f;
            float sc = act ? 1.f : 0.f;
#pragma unroll
            for (int m = 1; m < 64; m <<= 1) {
                ss += __shfl_xor(ss, m, 64);
                sc += __shfl_xor(sc, m, 64);
            }
            t = (ss - 1.0f) / sc;           // sc >= 1 (col max is a candidate)
            if (sc == prev) break;
            prev = sc;
        }
        if (v > t) out[(long)row * COLS + col] = v - t;   // out zeroed by C
    } else {
        // overflow fallback: exact Michelot over the full column + scatter
        const float s = -expf(a[0]);
        float t = -3.0e38f, prev = 0.f;
        for (int it = 0; it < 256; ++it) {
            float ss = 0.f, sc = 0.f;
            for (int i = 0; i < ROWS / 64; ++i) {
                const float zz = s * x[(long)(lane + i * 64) * COLS + col];
                if (zz > t) { ss += zz; sc += 1.f; }
            }
#pragma unroll
            for (int m = 1; m < 64; m <<= 1) {
                ss += __shfl_xor(ss, m, 64);
                sc += __shfl_xor(sc, m, 64);
            }
            t = (ss - 1.0f) / sc;
            if (sc == prev) break;
            prev = sc;
        }
        for (int i = 0; i < ROWS / 64; ++i) {
            const long r = lane + i * 64;
            const float zz = s * x[r * COLS + col];
            if (zz > t) out[r * COLS + col] = zz - t;
        }
    }
}

extern "C" void kernel_launch(void* const* d_in, const int* in_sizes, int n_in,
                              void* d_out, int out_size, void* d_ws, size_t ws_size,
                              hipStream_t stream) {
    const float* x = (const float*)d_in[0];
    const float* a = (const float*)d_in[1];
    float* out = (float*)d_out;

    char*   ws    = (char*)d_ws;
    int*    cnt   = (int*)ws;                        // 512 KB (padded counters)
    float*  thrx  = (float*)(ws + 512 * 1024);       // 32 KB
    float*  pminx = (float*)(ws + 1024 * 1024);      // 8 MiB
    float2* cand  = (float2*)(ws + 9 * 1024 * 1024); // 4 MiB

    hipLaunchKernelGGL(k_pmax,      dim3(NPA),         dim3(1024), 0, stream,
                       x, pminx, cnt);
    hipLaunchKernelGGL(k_reduce,    dim3(COLS / 256),  dim3(256),  0, stream,
                       pminx, a, thrx);
    hipLaunchKernelGGL(k_filterzero,dim3(ROWS / PANC), dim3(512),  0, stream,
                       x, a, thrx, cnt, cand, out);
    hipLaunchKernelGGL(k_solve,     dim3(COLS / 4),    dim3(256),  0, stream,
                       cnt, cand, x, a, out);
}